// Round 13
// baseline (241.697 us; speedup 1.0000x reference)
//
#include <hip/hip_runtime.h>
#include <stdint.h>

typedef __bf16 bf16;
typedef __attribute__((ext_vector_type(4))) float f32x4;
typedef __attribute__((ext_vector_type(16))) float f32x16;
typedef __attribute__((ext_vector_type(8))) bf16 bf16x8;
typedef __attribute__((ext_vector_type(4))) bf16 bf16x4;
typedef __attribute__((ext_vector_type(4))) float f4;

#define HQ_ 16
#define HKV_ 4
#define S_ 2048
#define D_ 2048

// async global->LDS, 16B per lane. lds_base must be wave-uniform; HW adds lane*16.
static __device__ __forceinline__ void gload16(const void* g, void* lds_base) {
  __builtin_amdgcn_global_load_lds(
      (const __attribute__((address_space(1))) void*)g,
      (__attribute__((address_space(3))) void*)lds_base, 16, 0, 0);
}

static __device__ __forceinline__ uint32_t pk2(float a, float b) {
  uint16_t lo = __builtin_bit_cast(uint16_t, (bf16)a);
  uint16_t hi = __builtin_bit_cast(uint16_t, (bf16)b);
  return (uint32_t)lo | ((uint32_t)hi << 16);
}

// ---------------- cast x: f32 -> bf16, 4 elems/thread ----------------
__global__ __launch_bounds__(256) void cast_x(const float* __restrict__ in,
                                              bf16* __restrict__ out, int n4) {
  int i = blockIdx.x * 256 + threadIdx.x;
  if (i >= n4) return;
  f4 v = *(const f4*)(in + (size_t)i * 4);
  bf16x4 o;
  o[0] = (bf16)v[0]; o[1] = (bf16)v[1]; o[2] = (bf16)v[2]; o[3] = (bf16)v[3];
  *(bf16x4*)(out + (size_t)i * 4) = o;
}

// ---- fused transpose+cast+scale of all four weights: W[K][N] -> Wt[N][K] ----
// blockIdx.x segments: [0,64) Wq | [64,80) Wk | [80,96) Wv | [96,160) Wo
__global__ __launch_bounds__(256)
void transWall(const float* __restrict__ Wq, const float* __restrict__ Wk,
               const float* __restrict__ Wv, const float* __restrict__ Wo,
               bf16* __restrict__ Wqt, bf16* __restrict__ Wkt,
               bf16* __restrict__ Wvt, bf16* __restrict__ Wot, float CQ) {
  __shared__ float tile[32][33];
  int bx = blockIdx.x;
  const float* W; bf16* Wt; int N, nx; float sc;
  if (bx < 64)      { W = Wq; Wt = Wqt; N = 2048; sc = CQ;   nx = bx; }
  else if (bx < 80) { W = Wk; Wt = Wkt; N = 512;  sc = 1.0f; nx = bx - 64; }
  else if (bx < 96) { W = Wv; Wt = Wvt; N = 512;  sc = 1.0f; nx = bx - 80; }
  else              { W = Wo; Wt = Wot; N = 2048; sc = 1.0f; nx = bx - 96; }
  int n0 = nx * 32, k0 = blockIdx.y * 32;
  int tx = threadIdx.x & 31, ty = threadIdx.x >> 5;
#pragma unroll
  for (int i = 0; i < 4; ++i)
    tile[ty + i * 8][tx] = W[(size_t)(k0 + ty + i * 8) * N + n0 + tx];
  __syncthreads();
#pragma unroll
  for (int i = 0; i < 4; ++i)
    Wt[(size_t)(n0 + ty + i * 8) * 2048 + k0 + tx] = (bf16)(tile[tx][ty + i * 8] * sc);
}

// ---------------- bf16 GEMM: C[M,N] = A[M,K] * Bt[N,K]^T ----------------
// 128x128 tile, BK=32, 4 waves (2x2), 16x16x32 MFMA, double-buffered LDS,
// counted vmcnt, raw s_barrier, XCD-chunked block swizzle (T1).  (unchanged)
// MODE 3: f32 row-major [M,N].  MODE 4: fused QKV epilogue (Q / K / V^T routing).
template <int MODE>
__global__ __launch_bounds__(256, 3)
void gemm128(const bf16* __restrict__ A, const bf16* __restrict__ Bt,
             void* __restrict__ out, void* __restrict__ out2,
             void* __restrict__ out3, int K, int N) {
  __shared__ __align__(16) bf16 As[2][128 * 32];
  __shared__ __align__(16) bf16 Bs[2][128 * 32];
  const int t = threadIdx.x;
  const int lane = t & 63, wave = t >> 6;
  const int l16 = lane & 15, l4 = lane >> 4;
  const int wr = wave >> 1, wc = wave & 1;

  const int gx = gridDim.x;
  const int flat = blockIdx.x + blockIdx.y * gx;
  const int chunk = (gx * gridDim.y) >> 3;
  const int lid = (flat & 7) * chunk + (flat >> 3);
  const int m0 = (lid / gx) * 128, n0 = (lid % gx) * 128;

  f32x4 acc[4][4] = {};

  const int r0 = t >> 2, c0 = ((t & 3) ^ ((t >> 3) & 3));
  const int r1 = r0 + 64, c1 = ((t & 3) ^ ((r1 >> 1) & 3));
  const bf16* aS0 = A + (size_t)(m0 + r0) * K + c0 * 8;
  const bf16* aS1 = A + (size_t)(m0 + r1) * K + c1 * 8;
  const bf16* bS0 = Bt + (size_t)(n0 + r0) * K + c0 * 8;
  const bf16* bS1 = Bt + (size_t)(n0 + r1) * K + c1 * 8;

  const int nk = K >> 5;
  auto STAGE = [&](int buf, int kt) {
    gload16(aS0 + (size_t)kt * 32, &As[buf][(wave * 64) * 8]);
    gload16(aS1 + (size_t)kt * 32, &As[buf][(256 + wave * 64) * 8]);
    gload16(bS0 + (size_t)kt * 32, &Bs[buf][(wave * 64) * 8]);
    gload16(bS1 + (size_t)kt * 32, &Bs[buf][(256 + wave * 64) * 8]);
  };

  STAGE(0, 0);
  int cb = 0;
  for (int kt = 0; kt < nk; ++kt) {
    int kn = kt + 1; if (kn == nk) kn = 0;
    STAGE(cb ^ 1, kn);
    asm volatile("s_waitcnt vmcnt(4)" ::: "memory");
    __builtin_amdgcn_s_barrier();
    bf16x8 af[4], bb[4];
#pragma unroll
    for (int mf = 0; mf < 4; ++mf) {
      int row = wr * 64 + mf * 16 + l16;
      af[mf] = *(const bf16x8*)&As[cb][row * 32 + (l4 ^ ((row >> 1) & 3)) * 8];
    }
#pragma unroll
    for (int nf = 0; nf < 4; ++nf) {
      int row = wc * 64 + nf * 16 + l16;
      bb[nf] = *(const bf16x8*)&Bs[cb][row * 32 + (l4 ^ ((row >> 1) & 3)) * 8];
    }
#pragma unroll
    for (int mf = 0; mf < 4; ++mf)
#pragma unroll
      for (int nf = 0; nf < 4; ++nf)
        acc[mf][nf] = __builtin_amdgcn_mfma_f32_16x16x32_bf16(af[mf], bb[nf],
                                                              acc[mf][nf], 0, 0, 0);
    __builtin_amdgcn_s_barrier();
    cb ^= 1;
  }

#pragma unroll
  for (int mf = 0; mf < 4; ++mf)
#pragma unroll
    for (int nf = 0; nf < 4; ++nf)
#pragma unroll
      for (int rg = 0; rg < 4; ++rg) {
        int r = m0 + wr * 64 + mf * 16 + l4 * 4 + rg;  // token index
        int c = n0 + wc * 64 + nf * 16 + l16;          // output column
        float v = acc[mf][nf][rg];
        if constexpr (MODE == 4) {
          int b = r >> 11, s = r & 2047;
          if (c < 2048) {                // Q: [B,HQ,S,128]
            int h = c >> 7, dd = c & 127;
            ((bf16*)out)[(((size_t)(b * HQ_ + h)) * S_ + s) * 128 + dd] = (bf16)v;
          } else if (c < 2560) {         // K: [B,HKV,S,128]
            int cc = c - 2048, h = cc >> 7, dd = cc & 127;
            ((bf16*)out2)[(((size_t)(b * HKV_ + h)) * S_ + s) * 128 + dd] = (bf16)v;
          } else {                       // V^T: [B,HKV,128,S]
            int cc = c - 2560, h = cc >> 7, dd = cc & 127;
            ((bf16*)out3)[(((size_t)(b * HKV_ + h)) * 128 + dd) * S_ + s] = (bf16)v;
          }
        } else {
          ((float*)out)[(size_t)r * N + c] = v;
        }
      }
}

// ---------------- flash attention, 32x32 MFMA, kk-split-2, 8 waves ----------------
// R5 geometry (proven correct) + R8's XCD swizzle (fixes R5's 234MB FETCH) +
// no-max softmax (makes the split merge trivial: l_total = l0 + l1) +
// K 3-buf / V 2-buf counted-vmcnt schedule. 512 thr: qsub=wave&3 (32 q-rows),
// kh=wave>>2 (32-kk half). 4096 waves -> 4 waves/SIMD (2x R12).
__global__ __launch_bounds__(512, 4)
void attn_fwd(const bf16* __restrict__ Qb, const bf16* __restrict__ Kb,
              const bf16* __restrict__ Vtb, bf16* __restrict__ AO) {
  __shared__ __align__(16) char smem[81920];
  bf16* KS = (bf16*)smem;              // 3 bufs x [64*128], 16B-chunk ^= kk&15
  bf16* VS = (bf16*)(smem + 49152);    // 2 bufs x [128*64], 16B-chunk ^= dd&7

  // XCD swizzle: 512 % 8 == 0 -> bijective; XCD i hosts one (b,hkv) stream.
  const int flat = blockIdx.x + (blockIdx.y << 4) + (blockIdx.z << 8);
  const int lid = (flat & 7) * 64 + (flat >> 3);
  const int qt = lid & 15, h = (lid >> 4) & 15, b = lid >> 8;
  const int hkv = h >> 2;  // REP = 4
  const int t = threadIdx.x, lane = t & 63, wave = t >> 6;
  const int l31 = lane & 31, l32 = lane >> 5;
  const int qsub = wave & 3, kh = wave >> 2;
  const bf16* Qg = Qb + ((size_t)(b * HQ_ + h) * S_ + qt * 128) * 128;
  const bf16* Kg = Kb + (size_t)(b * HKV_ + hkv) * S_ * 128;
  const bf16* Vg = Vtb + (size_t)(b * HKV_ + hkv) * 128 * S_;

  // Q frags (B-operand): lane: Q[q = qsub*32 + l31][d = ds*16 + l32*8 + e]
  bf16x8 qfr[8];
#pragma unroll
  for (int ds = 0; ds < 8; ++ds)
    qfr[ds] = *(const bf16x8*)&Qg[(size_t)(qsub * 32 + l31) * 128 + ds * 16 + l32 * 8];
  asm volatile("s_waitcnt vmcnt(0)" ::: "memory");  // drain Q: vmcnt counts stay exact

  // staging: 512 threads x 2 slots per matrix (pre-swizzled global source)
  const bf16* kp[2]; const bf16* vp[2];
#pragma unroll
  for (int i = 0; i < 2; ++i) {
    int s = i * 512 + t;
    int kr = s >> 4, klc = (s & 15) ^ (kr & 15);
    kp[i] = Kg + (size_t)kr * 128 + klc * 8;
    int vr = s >> 3, vlc = (s & 7) ^ (vr & 7);
    vp[i] = Vg + (size_t)vr * S_ + vlc * 8;
  }
  auto STAGE_K = [&](int buf, int nt) {
#pragma unroll
    for (int i = 0; i < 2; ++i)
      gload16(kp[i] + (size_t)nt * 8192, &KS[buf * 8192 + (i * 512 + wave * 64) * 8]);
  };
  auto STAGE_V = [&](int buf, int nt) {
#pragma unroll
    for (int i = 0; i < 2; ++i)
      gload16(vp[i] + nt * 64, &VS[buf * 8192 + (i * 512 + wave * 64) * 8]);
  };

  f32x16 ao[4] = {};
  float lrun = 0.f;
  const int krow = kh * 32 + l31;

  // prologue: K(0), V(0), K(1) = 6 loads; vmcnt(4) => K(0) landed
  STAGE_K(0, 0); STAGE_V(0, 0); STAGE_K(1, 1);
  asm volatile("s_waitcnt vmcnt(4)" ::: "memory");

  int ck = 0, cs = 2, cv = 0;
  for (int nt = 0; nt < S_ / 64; ++nt) {
    STAGE_K(cs, (nt + 2) & 31);          // K(t+2): buf held K(t-1), freed at M(t-1)
    __builtin_amdgcn_s_barrier();        // B: all waves' K(t) slices in LDS

    // ---- QK^T (wave's 32-kk half): scT += mfma(K-frag, Q-frag), 8 MFMA ----
    f32x16 scT = {};
    __builtin_amdgcn_s_setprio(1);
#pragma unroll
    for (int ds = 0; ds < 8; ++ds) {
      int lc = ds * 2 + l32;
      bf16x8 kb = *(const bf16x8*)&KS[ck * 8192 + krow * 128 + (lc ^ (l31 & 15)) * 8];
      scT = __builtin_amdgcn_mfma_f32_32x32x16_bf16(kb, qfr[ds], scT, 0, 0, 0);
    }
    __builtin_amdgcn_s_setprio(0);

    // ---- no-max softmax: p = exp2(s) (Q pre-scaled); lane-partial l ----
    float ssum = 0.f;
#pragma unroll
    for (int r = 0; r < 16; ++r) {
      float pv = __builtin_amdgcn_exp2f(scT[r]);
      scT[r] = pv;
      ssum += pv;
    }
    lrun += ssum;

    // ---- pack P pairs: u[g][j] covers kk_loc = 8g + 4*l32 + 2j, +1 ----
    uint32_t u[4][2];
#pragma unroll
    for (int g = 0; g < 4; ++g)
#pragma unroll
      for (int j = 0; j < 2; ++j)
        u[g][j] = pk2(scT[g * 4 + 2 * j], scT[g * 4 + 2 * j + 1]);

    // ---- permlane32_swap -> PV B-frags pb[bb]: P^T[kk_loc = bb*16+l32*8+e][q] ----
    bf16x8 pb[2];
#pragma unroll
    for (int bb = 0; bb < 2; ++bb) {
      uint32_t d0 = u[2 * bb][0], s0 = u[2 * bb + 1][0];
      uint32_t d1 = u[2 * bb][1], s1 = u[2 * bb + 1][1];
      asm volatile("v_permlane32_swap_b32 %0, %1" : "+v"(d0), "+v"(s0));
      asm volatile("v_permlane32_swap_b32 %0, %1" : "+v"(d1), "+v"(s1));
      uint4 w; w.x = d0; w.y = d1; w.z = s0; w.w = s1;
      pb[bb] = __builtin_bit_cast(bf16x8, w);
    }

    // V(t) wait: only K(t+2) (2 loads) younger => vmcnt(2); also forces K(t+1).
    asm volatile("s_waitcnt vmcnt(2)" ::: "memory");
    __builtin_amdgcn_s_barrier();        // M: all waves' V(t) in LDS; PV(t-1) done
    STAGE_V(cv ^ 1, (nt + 1) & 31);      // V(t+1): buf held V(t-1), freed at M

    // ---- PV: ao[df] += mfma(V^T-frag, pb[bb])  (kk = kh*32 + bb*16 + ...) ----
    __builtin_amdgcn_s_setprio(1);
#pragma unroll
    for (int bb = 0; bb < 2; ++bb) {
      int lc = kh * 4 + bb * 2 + l32;
#pragma unroll
      for (int df = 0; df < 4; ++df) {
        int dd = df * 32 + l31;
        bf16x8 va = *(const bf16x8*)&VS[cv * 8192 + dd * 64 + (lc ^ (dd & 7)) * 8];
        ao[df] = __builtin_amdgcn_mfma_f32_32x32x16_bf16(va, pb[bb], ao[df], 0, 0, 0);
      }
    }
    __builtin_amdgcn_s_setprio(0);

    ck = (ck == 2) ? 0 : ck + 1;
    cs = (cs == 2) ? 0 : cs + 1;
    cv ^= 1;
  }

  // ---- merge kk-halves (waves w and w^4 share q-rows); no-max => l adds ----
  asm volatile("s_waitcnt vmcnt(0)" ::: "memory");  // wrap-STAGE DMA still writing
  __builtin_amdgcn_s_barrier();
  float* aoex = (float*)smem;                 // [qsub*64+lane][64] f32 = 64 KB
  float* larr = (float*)(smem + 65536);       // [8][32]
  lrun += __shfl_xor(lrun, 32);
  if (l32 == 0) larr[wave * 32 + l31] = lrun;
  __builtin_amdgcn_s_barrier();
  float lsum = lrun + larr[(wave ^ 4) * 32 + l31];
  float* exch = aoex + ((size_t)(qsub * 64 + lane)) * 64;
  if (wave >= 4) {
#pragma unroll
    for (int df = 0; df < 4; ++df)
#pragma unroll
      for (int g = 0; g < 4; ++g) {
        f4 v;
#pragma unroll
        for (int j = 0; j < 4; ++j) v[j] = ao[df][4 * g + j];
        *(f4*)&exch[df * 16 + 4 * g] = v;
      }
  }
  __builtin_amdgcn_s_barrier();
  if (wave < 4) {
    float inv = 1.f / lsum;
    bf16* aop = AO + ((size_t)(b * S_ + qt * 128 + qsub * 32 + l31)) * D_ + h * 128;
#pragma unroll
    for (int df = 0; df < 4; ++df)
#pragma unroll
      for (int g = 0; g < 4; ++g) {
        f4 v = *(const f4*)&exch[df * 16 + 4 * g];
        bf16x4 o;
#pragma unroll
        for (int j = 0; j < 4; ++j) o[j] = (bf16)((ao[df][4 * g + j] + v[j]) * inv);
        *(bf16x4*)&aop[df * 32 + 8 * g + 4 * l32] = o;
      }
  }
}

extern "C" void kernel_launch(void* const* d_in, const int* in_sizes, int n_in,
                              void* d_out, int out_size, void* d_ws, size_t ws_size,
                              hipStream_t stream) {
  const float* x  = (const float*)d_in[0];
  const float* Wq = (const float*)d_in[1];
  const float* Wk = (const float*)d_in[2];
  const float* Wv = (const float*)d_in[3];
  const float* Wo = (const float*)d_in[4];

  char* ws = (char*)d_ws;
  bf16* xb  = (bf16*)(ws + 0);          // 16 MiB  [4096][2048]; reused as AO later
  bf16* Wqt = (bf16*)(ws + 16777216);   // 8 MiB   [2048][2048] (N-major)  } contiguous
  bf16* Wkt = (bf16*)(ws + 25165824);   // 2 MiB   [512][2048]             } 3072-row
  bf16* Wvt = (bf16*)(ws + 27262976);   // 2 MiB   [512][2048]             } QKV weight
  bf16* Wot = (bf16*)(ws + 29360128);   // 8 MiB   [2048][2048]
  bf16* Qb  = (bf16*)(ws + 37748736);   // 16 MiB  [B,HQ,S,128]
  bf16* Kb  = (bf16*)(ws + 54525952);   // 4 MiB   [B,HKV,S,128]
  bf16* Vtb = (bf16*)(ws + 58720256);   // 4 MiB   [B,HKV,128,S]
  bf16* AO  = xb;                       // alias: xb dead after QKV projection

  // fold log2(e)/sqrt(HEAD_DIM) into Wq so attention scores are exp2-ready
  const float CQ = 1.4426950408889634f * 0.08838834764831845f;

  cast_x<<<8192, 256, 0, stream>>>(x, xb, 2097152);
  transWall<<<dim3(160, 64), 256, 0, stream>>>(Wq, Wk, Wv, Wo, Wqt, Wkt, Wvt, Wot, CQ);

  // fused QKV projection: Bt = [Wqt; Wkt; Wvt] (3072 rows, contiguous)
  gemm128<4><<<dim3(24, 32), 256, 0, stream>>>(xb, Wqt, (void*)Qb, (void*)Kb,
                                               (void*)Vtb, 2048, 3072);

  attn_fwd<<<dim3(16, 16, 2), 512, 0, stream>>>(Qb, Kb, Vtb, AO);

  gemm128<3><<<dim3(16, 32), 256, 0, stream>>>(AO, Wot, d_out, nullptr, nullptr,
                                               2048, 2048);
}

// Round 14
// 212.875 us; speedup vs baseline: 1.1354x; 1.1354x over previous
//
#include <hip/hip_runtime.h>
#include <stdint.h>

typedef __bf16 bf16;
typedef __attribute__((ext_vector_type(4))) float f32x4;
typedef __attribute__((ext_vector_type(16))) float f32x16;
typedef __attribute__((ext_vector_type(8))) bf16 bf16x8;
typedef __attribute__((ext_vector_type(4))) bf16 bf16x4;
typedef __attribute__((ext_vector_type(4))) float f4;

#define HQ_ 16
#define HKV_ 4
#define S_ 2048
#define D_ 2048

// async global->LDS, 16B per lane. lds_base must be wave-uniform; HW adds lane*16.
static __device__ __forceinline__ void gload16(const void* g, void* lds_base) {
  __builtin_amdgcn_global_load_lds(
      (const __attribute__((address_space(1))) void*)g,
      (__attribute__((address_space(3))) void*)lds_base, 16, 0, 0);
}

static __device__ __forceinline__ uint32_t pk2(float a, float b) {
  uint16_t lo = __builtin_bit_cast(uint16_t, (bf16)a);
  uint16_t hi = __builtin_bit_cast(uint16_t, (bf16)b);
  return (uint32_t)lo | ((uint32_t)hi << 16);
}

// ---- fused prep: cast x (blocks [0,8192)) + transpose weights ([8192,18432)) ----
// cast: x f32 -> xb bf16, 4 elems/thread.
// transW: W[K][N] f32 -> Wt[N][2048] bf16 (+scale); segments per original transWall.
__global__ __launch_bounds__(256)
void prepAll(const float* __restrict__ x, bf16* __restrict__ xb,
             const float* __restrict__ Wq, const float* __restrict__ Wk,
             const float* __restrict__ Wv, const float* __restrict__ Wo,
             bf16* __restrict__ Wqt, bf16* __restrict__ Wkt,
             bf16* __restrict__ Wvt, bf16* __restrict__ Wot, float CQ) {
  __shared__ float tile[32][33];
  int bid = blockIdx.x;
  if (bid < 8192) {
    int i = bid * 256 + threadIdx.x;
    f4 v = *(const f4*)(x + (size_t)i * 4);
    bf16x4 o;
    o[0] = (bf16)v[0]; o[1] = (bf16)v[1]; o[2] = (bf16)v[2]; o[3] = (bf16)v[3];
    *(bf16x4*)(xb + (size_t)i * 4) = o;
    return;
  }
  int tw = bid - 8192;
  int bx = tw % 160, ky = tw / 160;
  const float* W; bf16* Wt; int N, nx; float sc;
  if (bx < 64)      { W = Wq; Wt = Wqt; N = 2048; sc = CQ;   nx = bx; }
  else if (bx < 80) { W = Wk; Wt = Wkt; N = 512;  sc = 1.0f; nx = bx - 64; }
  else if (bx < 96) { W = Wv; Wt = Wvt; N = 512;  sc = 1.0f; nx = bx - 80; }
  else              { W = Wo; Wt = Wot; N = 2048; sc = 1.0f; nx = bx - 96; }
  int n0 = nx * 32, k0 = ky * 32;
  int tx = threadIdx.x & 31, ty = threadIdx.x >> 5;
#pragma unroll
  for (int i = 0; i < 4; ++i)
    tile[ty + i * 8][tx] = W[(size_t)(k0 + ty + i * 8) * N + n0 + tx];
  __syncthreads();
#pragma unroll
  for (int i = 0; i < 4; ++i)
    Wt[(size_t)(n0 + ty + i * 8) * 2048 + k0 + tx] = (bf16)(tile[tx][ty + i * 8] * sc);
}

// ---------------- bf16 GEMM: C[M,N] = A[M,K] * Bt[N,K]^T ----------------
// 128x128 tile, BK=32, 4 waves (2x2), 16x16x32 MFMA, double-buffered LDS,
// counted vmcnt, raw s_barrier, XCD-chunked block swizzle (T1).  (R12 verbatim)
// MODE 3: f32 row-major [M,N].  MODE 4: fused QKV epilogue (Q / K / V^T routing).
template <int MODE>
__global__ __launch_bounds__(256, 3)
void gemm128(const bf16* __restrict__ A, const bf16* __restrict__ Bt,
             void* __restrict__ out, void* __restrict__ out2,
             void* __restrict__ out3, int K, int N) {
  __shared__ __align__(16) bf16 As[2][128 * 32];
  __shared__ __align__(16) bf16 Bs[2][128 * 32];
  const int t = threadIdx.x;
  const int lane = t & 63, wave = t >> 6;
  const int l16 = lane & 15, l4 = lane >> 4;
  const int wr = wave >> 1, wc = wave & 1;

  const int gx = gridDim.x;
  const int flat = blockIdx.x + blockIdx.y * gx;
  const int chunk = (gx * gridDim.y) >> 3;
  const int lid = (flat & 7) * chunk + (flat >> 3);
  const int m0 = (lid / gx) * 128, n0 = (lid % gx) * 128;

  f32x4 acc[4][4] = {};

  const int r0 = t >> 2, c0 = ((t & 3) ^ ((t >> 3) & 3));
  const int r1 = r0 + 64, c1 = ((t & 3) ^ ((r1 >> 1) & 3));
  const bf16* aS0 = A + (size_t)(m0 + r0) * K + c0 * 8;
  const bf16* aS1 = A + (size_t)(m0 + r1) * K + c1 * 8;
  const bf16* bS0 = Bt + (size_t)(n0 + r0) * K + c0 * 8;
  const bf16* bS1 = Bt + (size_t)(n0 + r1) * K + c1 * 8;

  const int nk = K >> 5;
  auto STAGE = [&](int buf, int kt) {
    gload16(aS0 + (size_t)kt * 32, &As[buf][(wave * 64) * 8]);
    gload16(aS1 + (size_t)kt * 32, &As[buf][(256 + wave * 64) * 8]);
    gload16(bS0 + (size_t)kt * 32, &Bs[buf][(wave * 64) * 8]);
    gload16(bS1 + (size_t)kt * 32, &Bs[buf][(256 + wave * 64) * 8]);
  };

  STAGE(0, 0);
  int cb = 0;
  for (int kt = 0; kt < nk; ++kt) {
    int kn = kt + 1; if (kn == nk) kn = 0;
    STAGE(cb ^ 1, kn);
    asm volatile("s_waitcnt vmcnt(4)" ::: "memory");
    __builtin_amdgcn_s_barrier();
    bf16x8 af[4], bb[4];
#pragma unroll
    for (int mf = 0; mf < 4; ++mf) {
      int row = wr * 64 + mf * 16 + l16;
      af[mf] = *(const bf16x8*)&As[cb][row * 32 + (l4 ^ ((row >> 1) & 3)) * 8];
    }
#pragma unroll
    for (int nf = 0; nf < 4; ++nf) {
      int row = wc * 64 + nf * 16 + l16;
      bb[nf] = *(const bf16x8*)&Bs[cb][row * 32 + (l4 ^ ((row >> 1) & 3)) * 8];
    }
#pragma unroll
    for (int mf = 0; mf < 4; ++mf)
#pragma unroll
      for (int nf = 0; nf < 4; ++nf)
        acc[mf][nf] = __builtin_amdgcn_mfma_f32_16x16x32_bf16(af[mf], bb[nf],
                                                              acc[mf][nf], 0, 0, 0);
    __builtin_amdgcn_s_barrier();
    cb ^= 1;
  }

#pragma unroll
  for (int mf = 0; mf < 4; ++mf)
#pragma unroll
    for (int nf = 0; nf < 4; ++nf)
#pragma unroll
      for (int rg = 0; rg < 4; ++rg) {
        int r = m0 + wr * 64 + mf * 16 + l4 * 4 + rg;  // token index
        int c = n0 + wc * 64 + nf * 16 + l16;          // output column
        float v = acc[mf][nf][rg];
        if constexpr (MODE == 4) {
          int b = r >> 11, s = r & 2047;
          if (c < 2048) {                // Q: [B,HQ,S,128]
            int h = c >> 7, dd = c & 127;
            ((bf16*)out)[(((size_t)(b * HQ_ + h)) * S_ + s) * 128 + dd] = (bf16)v;
          } else if (c < 2560) {         // K: [B,HKV,S,128]
            int cc = c - 2048, h = cc >> 7, dd = cc & 127;
            ((bf16*)out2)[(((size_t)(b * HKV_ + h)) * S_ + s) * 128 + dd] = (bf16)v;
          } else {                       // V^T: [B,HKV,128,S]
            int cc = c - 2560, h = cc >> 7, dd = cc & 127;
            ((bf16*)out3)[(((size_t)(b * HKV_ + h)) * 128 + dd) * S_ + s] = (bf16)v;
          }
        } else {
          ((float*)out)[(size_t)r * N + c] = v;
        }
      }
}

// ---------------- flash attention, 32x32 MFMA, T15 two-tile pipeline ----------------
// R12 verbatim (proven 84.9 us): KVBLK=64, K 3-buf, V 2-buf, no-max softmax,
// XCD swizzle; iteration t runs QK^T(t+1) [MFMA] alongside softmax(t) [VALU],
// then PV(t). Scores ping-pong in named sA/sB.
__global__ __launch_bounds__(256, 2)
void attn_fwd(const bf16* __restrict__ Qb, const bf16* __restrict__ Kb,
              const bf16* __restrict__ Vtb, bf16* __restrict__ AO) {
  __shared__ __align__(16) bf16 KS[3][64 * 128];   // [kk][d], 16B-chunk ^= kk&15
  __shared__ __align__(16) bf16 VS[2][128 * 64];   // [dd][kk], 16B-chunk ^= dd&7

  // XCD swizzle: 512 % 8 == 0 -> bijective; XCD i hosts one (b,hkv) stream.
  const int flat = blockIdx.x + (blockIdx.y << 4) + (blockIdx.z << 8);
  const int lid = (flat & 7) * 64 + (flat >> 3);
  const int qt = lid & 15, h = (lid >> 4) & 15, b = lid >> 8;
  const int hkv = h >> 2;  // REP = 4
  const int t = threadIdx.x, lane = t & 63, wave = t >> 6;
  const int l31 = lane & 31, l32 = lane >> 5;
  const bf16* Qg = Qb + ((size_t)(b * HQ_ + h) * S_ + qt * 128) * 128;
  const bf16* Kg = Kb + (size_t)(b * HKV_ + hkv) * S_ * 128;
  const bf16* Vg = Vtb + (size_t)(b * HKV_ + hkv) * 128 * S_;

  // Q frags (B-operand): lane: Q[q = wave*32 + l31][d = ds*16 + l32*8 + e]
  bf16x8 qfr[8];
#pragma unroll
  for (int ds = 0; ds < 8; ++ds)
    qfr[ds] = *(const bf16x8*)&Qg[(size_t)(wave * 32 + l31) * 128 + ds * 16 + l32 * 8];
  asm volatile("s_waitcnt vmcnt(0)" ::: "memory");  // drain Q: vmcnt counts stay exact

  // staging bases (pre-swizzled global source, linear LDS dest)
  const bf16* kp[4]; const bf16* vp[4];
#pragma unroll
  for (int i = 0; i < 4; ++i) {
    int s = i * 256 + t;
    int kr = s >> 4, klc = (s & 15) ^ (kr & 15);
    kp[i] = Kg + (size_t)kr * 128 + klc * 8;
    int vr = s >> 3, vlc = (s & 7) ^ (vr & 7);
    vp[i] = Vg + (size_t)vr * S_ + vlc * 8;
  }
  auto STAGE_K = [&](int buf, int nt) {
#pragma unroll
    for (int i = 0; i < 4; ++i)
      gload16(kp[i] + (size_t)nt * 8192, &KS[buf][(i * 256 + wave * 64) * 8]);
  };
  auto STAGE_V = [&](int buf, int nt) {
#pragma unroll
    for (int i = 0; i < 4; ++i)
      gload16(vp[i] + nt * 64, &VS[buf][(i * 256 + wave * 64) * 8]);
  };

  f32x16 ao[4] = {};
  float lrun = 0.f;

  // QK^T(tile) from KS[buf] into dst (S^T = mfma(K, Q))
  auto QKT = [&](int buf, f32x16 (&dst)[2]) {
    f32x16 z = {};
    dst[0] = z; dst[1] = z;
#pragma unroll
    for (int ds = 0; ds < 8; ++ds) {
      int lc = ds * 2 + l32;
      bf16x8 kb0 = *(const bf16x8*)&KS[buf][l31 * 128 + (lc ^ (l31 & 15)) * 8];
      bf16x8 kb1 = *(const bf16x8*)&KS[buf][(32 + l31) * 128 + (lc ^ (l31 & 15)) * 8];
      dst[0] = __builtin_amdgcn_mfma_f32_32x32x16_bf16(kb0, qfr[ds], dst[0], 0, 0, 0);
      dst[1] = __builtin_amdgcn_mfma_f32_32x32x16_bf16(kb1, qfr[ds], dst[1], 0, 0, 0);
    }
  };

  // no-max softmax + pack + permlane -> PV B-frags
  auto SMAX = [&](f32x16 (&cur)[2], bf16x8 (&pb)[4]) {
    float ssum = 0.f;
#pragma unroll
    for (int kf = 0; kf < 2; ++kf)
#pragma unroll
      for (int r = 0; r < 16; ++r) {
        float pv = __builtin_amdgcn_exp2f(cur[kf][r]);
        cur[kf][r] = pv;
        ssum += pv;
      }
    lrun += ssum;
    uint32_t u[2][4][2];
#pragma unroll
    for (int kf = 0; kf < 2; ++kf)
#pragma unroll
      for (int g = 0; g < 4; ++g)
#pragma unroll
        for (int j = 0; j < 2; ++j)
          u[kf][g][j] = pk2(cur[kf][g * 4 + 2 * j], cur[kf][g * 4 + 2 * j + 1]);
#pragma unroll
    for (int ks = 0; ks < 4; ++ks) {
      int kf = ks >> 1, bb = ks & 1;
      uint32_t d0 = u[kf][2 * bb][0], s0 = u[kf][2 * bb + 1][0];
      uint32_t d1 = u[kf][2 * bb][1], s1 = u[kf][2 * bb + 1][1];
      asm volatile("v_permlane32_swap_b32 %0, %1" : "+v"(d0), "+v"(s0));
      asm volatile("v_permlane32_swap_b32 %0, %1" : "+v"(d1), "+v"(s1));
      uint4 w; w.x = d0; w.y = d1; w.z = s0; w.w = s1;
      pb[ks] = __builtin_bit_cast(bf16x8, w);
    }
  };

  auto PV = [&](int vbuf, bf16x8 (&pb)[4]) {
    __builtin_amdgcn_s_setprio(1);
#pragma unroll
    for (int ks = 0; ks < 4; ++ks) {
      int lc = ks * 2 + l32;
#pragma unroll
      for (int df = 0; df < 4; ++df) {
        int dd = df * 32 + l31;
        bf16x8 va = *(const bf16x8*)&VS[vbuf][dd * 64 + (lc ^ (dd & 7)) * 8];
        ao[df] = __builtin_amdgcn_mfma_f32_32x32x16_bf16(va, pb[ks], ao[df], 0, 0, 0);
      }
    }
    __builtin_amdgcn_s_setprio(0);
  };

  // prologue: K(0), K(1), V(0) (this order makes iter-0 vmcnt == steady state)
  STAGE_K(0, 0); STAGE_K(1, 1); STAGE_V(0, 0);
  asm volatile("s_waitcnt vmcnt(8)" ::: "memory");  // K(0) landed
  __builtin_amdgcn_s_barrier();

  f32x16 sA[2], sB[2];
  QKT(0, sA);

  // iteration t: softmax(t) || QK^T(t+1), then PV(t).
  auto BODY = [&](int tt, f32x16 (&cur)[2], f32x16 (&nxt)[2]) {
    STAGE_K((tt + 2) % 3, (tt + 2) & 31);
    asm volatile("s_waitcnt vmcnt(8)" ::: "memory");  // K(t+1) landed (V(t),K(t+2) fly)
    __builtin_amdgcn_s_barrier();
    QKT((tt + 1) % 3, nxt);            // MFMA pipe
    bf16x8 pb[4];
    SMAX(cur, pb);                     // VALU pipe (independent -> overlaps)
    asm volatile("s_waitcnt vmcnt(4)" ::: "memory");  // V(t) landed (K(t+2) flies)
    __builtin_amdgcn_s_barrier();
    STAGE_V((tt + 1) & 1, (tt + 1) & 31);
    PV(tt & 1, pb);
  };

  for (int nt = 0; nt < 30; nt += 2) {
    BODY(nt, sA, sB);
    BODY(nt + 1, sB, sA);
  }
  BODY(30, sA, sB);                    // leaves scores(31) in sB

  // tail: tile 31 (no next QK^T)
  {
    bf16x8 pb[4];
    SMAX(sB, pb);
    asm volatile("s_waitcnt vmcnt(0)" ::: "memory");  // V(31) landed
    __builtin_amdgcn_s_barrier();
    PV(1, pb);                         // 31 & 1 = 1
  }

  // ---- epilogue: merge lane halves of l; lane holds O^T[dd][q=l31] ----
  lrun += __shfl_xor(lrun, 32);
  float inv = 1.f / lrun;
  bf16* aop = AO + ((size_t)(b * S_ + qt * 128 + wave * 32 + l31)) * D_ + h * 128;
#pragma unroll
  for (int df = 0; df < 4; ++df)
#pragma unroll
    for (int g = 0; g < 4; ++g) {
      bf16x4 o;
#pragma unroll
      for (int j = 0; j < 4; ++j) o[j] = (bf16)(ao[df][4 * g + j] * inv);
      *(bf16x4*)&aop[df * 32 + 8 * g + 4 * l32] = o;
    }
}

extern "C" void kernel_launch(void* const* d_in, const int* in_sizes, int n_in,
                              void* d_out, int out_size, void* d_ws, size_t ws_size,
                              hipStream_t stream) {
  const float* x  = (const float*)d_in[0];
  const float* Wq = (const float*)d_in[1];
  const float* Wk = (const float*)d_in[2];
  const float* Wv = (const float*)d_in[3];
  const float* Wo = (const float*)d_in[4];

  char* ws = (char*)d_ws;
  bf16* xb  = (bf16*)(ws + 0);          // 16 MiB  [4096][2048]; reused as AO later
  bf16* Wqt = (bf16*)(ws + 16777216);   // 8 MiB   [2048][2048] (N-major)  } contiguous
  bf16* Wkt = (bf16*)(ws + 25165824);   // 2 MiB   [512][2048]             } 3072-row
  bf16* Wvt = (bf16*)(ws + 27262976);   // 2 MiB   [512][2048]             } QKV weight
  bf16* Wot = (bf16*)(ws + 29360128);   // 8 MiB   [2048][2048]
  bf16* Qb  = (bf16*)(ws + 37748736);   // 16 MiB  [B,HQ,S,128]
  bf16* Kb  = (bf16*)(ws + 54525952);   // 4 MiB   [B,HKV,S,128]
  bf16* Vtb = (bf16*)(ws + 58720256);   // 4 MiB   [B,HKV,128,S]
  bf16* AO  = xb;                       // alias: xb dead after QKV projection

  // fold log2(e)/sqrt(HEAD_DIM) into Wq so attention scores are exp2-ready
  const float CQ = 1.4426950408889634f * 0.08838834764831845f;

  // fused prep: cast x + transpose all weights, one dispatch
  prepAll<<<18432, 256, 0, stream>>>(x, xb, Wq, Wk, Wv, Wo,
                                     Wqt, Wkt, Wvt, Wot, CQ);

  // fused QKV projection: Bt = [Wqt; Wkt; Wvt] (3072 rows, contiguous)
  gemm128<4><<<dim3(24, 32), 256, 0, stream>>>(xb, Wqt, (void*)Qb, (void*)Kb,
                                               (void*)Vtb, 2048, 3072);

  attn_fwd<<<dim3(16, 16, 2), 256, 0, stream>>>(Qb, Kb, Vtb, AO);

  gemm128<3><<<dim3(16, 32), 256, 0, stream>>>(AO, Wot, d_out, nullptr, nullptr,
                                               2048, 2048);
}